// Round 4
// baseline (173.876 us; speedup 1.0000x reference)
//
#include <hip/hip_runtime.h>

// GCN 2-layer. out = tanh((Â x) W1 + b1) W2 + b2, with Â(xW1)=(Âx)W1.
// Round 15: no compaction. agg reads XCD-partitioned buckets (col8) directly.
//  k1: partitioned scatter (p=blockIdx&7 -> XCD-local L2, no line bounce)
//      + xb = bf16(x) raw (no dinv; streams under atomic latency) + zero row
//      + W frag swizzle.
//  k2 (tiny): pcnt[i] = packed 8x uint8 per-partition counts; dinv[N+1] f32
//      table (dinv[N] = 0 -> sentinel slots weigh 0 automatically).
//  k3: agg gathers xb rows + dinv[src] (fma, 200KB L2-hot table); 8 quad0s
//      preloaded -> 32 gathers in flight; empty slots clamp to sentinel N;
//      rare fixup quads for d_p>4. Then GEMM1(+bias+tanh) -> GEMM2(+bias).
// 4 graph nodes: memset(cnt8) | k1 | k2 | k3.
// ws: cnt8(1.6MB) | col8(25.6) | pcnt(0.4) | dinv(0.2) | xb(12.8) | w1f | w2f

#define DFEAT 128
#define CAP8 16     // per-partition capacity (lambda=1.6, P(overflow)~1e-12)
#define NPART 8
#define BROWS 32    // nodes per block

typedef __attribute__((ext_vector_type(8))) short short8;
typedef __attribute__((ext_vector_type(4))) float float4v;

__device__ __forceinline__ float bflo(unsigned int u) {
    union { unsigned int i; float f; } v; v.i = u << 16; return v.f;
}
__device__ __forceinline__ float bfhi(unsigned int u) {
    union { unsigned int i; float f; } v; v.i = u & 0xffff0000u; return v.f;
}
__device__ __forceinline__ unsigned short f2bf(float f) {
    union { unsigned int i; float f; } v; v.f = f;
    unsigned int r = v.i + 0x7fffu + ((v.i >> 16) & 1u);  // RNE
    return (unsigned short)(r >> 16);
}
__device__ __forceinline__ unsigned int pack2(float a, float b) {
    return (unsigned int)f2bf(a) | ((unsigned int)f2bf(b) << 16);
}
// tanh(x) = 1 - 2/(exp(2x)+1); exact at +-inf.
__device__ __forceinline__ float fast_tanh(float x) {
    float e = __expf(2.0f * x);
    float r = __builtin_amdgcn_rcpf(e + 1.0f);  // raw v_rcp_f32, ~1 ulp
    return __builtin_fmaf(-2.0f, r, 1.0f);
}

// k1: partitioned count+scatter + xb = bf16(x) + zero row + W frag swizzle.
__global__ void k1_scatter_conv(const int* __restrict__ src, const int* __restrict__ dst,
                                int* __restrict__ cnt8, int* __restrict__ col8,
                                const float* __restrict__ x, unsigned int* __restrict__ xb2,
                                const float* __restrict__ W1, const float* __restrict__ W2,
                                unsigned short* __restrict__ w1f, unsigned short* __restrict__ w2f,
                                int e, int n32, int n) {
    int i = blockIdx.x * blockDim.x + threadIdx.x;
    if (i < 2 * DFEAT * DFEAT) {  // W fragment swizzle (B-operand layout)
        int which = i >> 14;
        int idx = i & 16383;
        int k = idx >> 7, nn = idx & 127;
        int f = ((nn >> 4) << 2) + (k >> 5);
        int lane = (nn & 15) | (((k >> 3) & 3) << 4);
        int j = k & 7;
        int o = f * 512 + lane * 8 + j;
        if (which == 0) w1f[o] = f2bf(W1[idx]);
        else            w2f[o] = f2bf(W2[idx]);
    }
    if (i < e) {
        int p = blockIdx.x & (NPART - 1);  // ~XCD id (perf-only assumption)
        int d = dst[i];
        int cell = p * n + d;
        int q = atomicAdd(&cnt8[cell], 1);
        if (q < CAP8) col8[(size_t)cell * CAP8 + q] = src[i];
    }
    if (i < n32) {  // xb = bf16(x), 4 floats per thread (no dinv)
        float4 v = ((const float4*)x)[i];
        xb2[i * 2]     = pack2(v.x, v.y);
        xb2[i * 2 + 1] = pack2(v.z, v.w);
    } else if (i < n32 + 32) {  // zero row xb[n] (sentinel target)
        xb2[i * 2] = 0u;
        xb2[i * 2 + 1] = 0u;
    }
}

// k2: pcnt[i] = 8 packed uint8 clamped partition counts; dinv table (f32).
__global__ void k2_desc(const int* __restrict__ cnt8, uint2* __restrict__ pcnt,
                        float* __restrict__ dinv, int n) {
    int i = blockIdx.x * blockDim.x + threadIdx.x;
    if (i < n) {
        unsigned int lo = 0, hi = 0;
        int tot = 0;
        #pragma unroll
        for (int p = 0; p < 4; ++p) {
            int c = min(cnt8[p * n + i], CAP8);
            tot += c; lo |= (unsigned int)c << (8 * p);
        }
        #pragma unroll
        for (int p = 4; p < 8; ++p) {
            int c = min(cnt8[p * n + i], CAP8);
            tot += c; hi |= (unsigned int)c << (8 * (p - 4));
        }
        pcnt[i] = make_uint2(lo, hi);
        dinv[i] = rsqrtf((float)(tot + 1));  // +1 self-loop
    } else if (i == n) {
        dinv[n] = 0.f;  // sentinel weight
    }
}

// k3: per-block aggregation of BROWS nodes into LDS, then
// GEMM1(+bias+tanh) -> LDS -> GEMM2(+bias) -> fp32 out.
// Gather: 2 passes x (16 nodes x 16 lanes); per node 8 partitions x quad0
// preloaded (32 row gathers in flight), empty slots -> sentinel n (dinv=0);
// fixup quads for d_p>4 (rare). fma with dinv[src] (L2-hot 200KB table).
// GEMM: wave w = (strip=w>>1) x (colh=w&1); A[m=lane&15][k=(lane>>4)*8+j];
// D: col=lane&15, row=(lane>>4)*4+reg (m89-verified layouts).
__global__ __launch_bounds__(256) void k_agg_gemm(
    const uint4* __restrict__ xb4, const uint2* __restrict__ pcnt,
    const float* __restrict__ dinv_t, const int* __restrict__ col8,
    const unsigned short* __restrict__ w1f, const float* __restrict__ b1,
    const unsigned short* __restrict__ w2f, const float* __restrict__ b2,
    float* __restrict__ out, int n) {
    __shared__ unsigned short aggs[BROWS * 136];  // 8.7 KB, 136-pitch
    __shared__ unsigned short hs[BROWS * 136];    // 8.7 KB
    const int t = threadIdx.x;
    const int4* c8 = (const int4*)col8;  // CAP8=16 ints = 4 int4 per cell

    // ---- aggregation phase ----
    const int lane16 = t & 15;
    const int sub = t >> 4;  // 0..15
    for (int g = 0; g < BROWS / 16; ++g) {
        int node_local = g * 16 + sub;
        int node = blockIdx.x * BROWS + node_local;
        int nodec = min(node, n - 1);
        uint2 pc = pcnt[nodec];
        float di = dinv_t[nodec];
        uint4 v = xb4[(size_t)nodec * 16 + lane16];  // self term (raw bf16)
        float a0 = bflo(v.x) * di, a1 = bfhi(v.x) * di;
        float a2 = bflo(v.y) * di, a3 = bfhi(v.y) * di;
        float a4 = bflo(v.z) * di, a5 = bfhi(v.z) * di;
        float a6 = bflo(v.w) * di, a7 = bfhi(v.w) * di;

        int4 s[NPART];  // quad0 of each partition, preloaded (32 gathers in flight)
        #pragma unroll
        for (int p = 0; p < NPART; ++p)
            s[p] = c8[(size_t)(p * n + nodec) * 4];

        #pragma unroll
        for (int p = 0; p < NPART; ++p) {
            int dp = (int)((p < 4 ? (pc.x >> (8 * p)) : (pc.y >> (8 * (p - 4)))) & 0xffu);
            int i0 = dp > 0 ? s[p].x : n;
            int i1 = dp > 1 ? s[p].y : n;
            int i2 = dp > 2 ? s[p].z : n;
            int i3 = dp > 3 ? s[p].w : n;
            float d0 = dinv_t[i0], d1 = dinv_t[i1], d2 = dinv_t[i2], d3 = dinv_t[i3];
            uint4 u0 = xb4[(size_t)i0 * 16 + lane16];
            uint4 u1 = xb4[(size_t)i1 * 16 + lane16];
            uint4 u2 = xb4[(size_t)i2 * 16 + lane16];
            uint4 u3 = xb4[(size_t)i3 * 16 + lane16];
            a0 = __builtin_fmaf(bflo(u0.x), d0, a0); a1 = __builtin_fmaf(bfhi(u0.x), d0, a1);
            a2 = __builtin_fmaf(bflo(u0.y), d0, a2); a3 = __builtin_fmaf(bfhi(u0.y), d0, a3);
            a4 = __builtin_fmaf(bflo(u0.z), d0, a4); a5 = __builtin_fmaf(bfhi(u0.z), d0, a5);
            a6 = __builtin_fmaf(bflo(u0.w), d0, a6); a7 = __builtin_fmaf(bfhi(u0.w), d0, a7);
            a0 = __builtin_fmaf(bflo(u1.x), d1, a0); a1 = __builtin_fmaf(bfhi(u1.x), d1, a1);
            a2 = __builtin_fmaf(bflo(u1.y), d1, a2); a3 = __builtin_fmaf(bfhi(u1.y), d1, a3);
            a4 = __builtin_fmaf(bflo(u1.z), d1, a4); a5 = __builtin_fmaf(bfhi(u1.z), d1, a5);
            a6 = __builtin_fmaf(bflo(u1.w), d1, a6); a7 = __builtin_fmaf(bfhi(u1.w), d1, a7);
            a0 = __builtin_fmaf(bflo(u2.x), d2, a0); a1 = __builtin_fmaf(bfhi(u2.x), d2, a1);
            a2 = __builtin_fmaf(bflo(u2.y), d2, a2); a3 = __builtin_fmaf(bfhi(u2.y), d2, a3);
            a4 = __builtin_fmaf(bflo(u2.z), d2, a4); a5 = __builtin_fmaf(bfhi(u2.z), d2, a5);
            a6 = __builtin_fmaf(bflo(u2.w), d2, a6); a7 = __builtin_fmaf(bfhi(u2.w), d2, a7);
            a0 = __builtin_fmaf(bflo(u3.x), d3, a0); a1 = __builtin_fmaf(bfhi(u3.x), d3, a1);
            a2 = __builtin_fmaf(bflo(u3.y), d3, a2); a3 = __builtin_fmaf(bfhi(u3.y), d3, a3);
            a4 = __builtin_fmaf(bflo(u3.z), d3, a4); a5 = __builtin_fmaf(bfhi(u3.z), d3, a5);
            a6 = __builtin_fmaf(bflo(u3.w), d3, a6); a7 = __builtin_fmaf(bfhi(u3.w), d3, a7);
        }
        // fixup quads for partitions with d_p > 4 (P~2.4% per partition)
        #pragma unroll
        for (int p = 0; p < NPART; ++p) {
            int dp = (int)((p < 4 ? (pc.x >> (8 * p)) : (pc.y >> (8 * (p - 4)))) & 0xffu);
            for (int b = 4; b < dp; b += 4) {
                int4 sq = c8[(size_t)(p * n + nodec) * 4 + (b >> 2)];
                int i0 = sq.x;                      // b < dp by loop condition
                int i1 = (b + 1) < dp ? sq.y : n;
                int i2 = (b + 2) < dp ? sq.z : n;
                int i3 = (b + 3) < dp ? sq.w : n;
                float d0 = dinv_t[i0], d1 = dinv_t[i1], d2 = dinv_t[i2], d3 = dinv_t[i3];
                uint4 u0 = xb4[(size_t)i0 * 16 + lane16];
                uint4 u1 = xb4[(size_t)i1 * 16 + lane16];
                uint4 u2 = xb4[(size_t)i2 * 16 + lane16];
                uint4 u3 = xb4[(size_t)i3 * 16 + lane16];
                a0 = __builtin_fmaf(bflo(u0.x), d0, a0); a1 = __builtin_fmaf(bfhi(u0.x), d0, a1);
                a2 = __builtin_fmaf(bflo(u0.y), d0, a2); a3 = __builtin_fmaf(bfhi(u0.y), d0, a3);
                a4 = __builtin_fmaf(bflo(u0.z), d0, a4); a5 = __builtin_fmaf(bfhi(u0.z), d0, a5);
                a6 = __builtin_fmaf(bflo(u0.w), d0, a6); a7 = __builtin_fmaf(bfhi(u0.w), d0, a7);
                a0 = __builtin_fmaf(bflo(u1.x), d1, a0); a1 = __builtin_fmaf(bfhi(u1.x), d1, a1);
                a2 = __builtin_fmaf(bflo(u1.y), d1, a2); a3 = __builtin_fmaf(bfhi(u1.y), d1, a3);
                a4 = __builtin_fmaf(bflo(u1.z), d1, a4); a5 = __builtin_fmaf(bfhi(u1.z), d1, a5);
                a6 = __builtin_fmaf(bflo(u1.w), d1, a6); a7 = __builtin_fmaf(bfhi(u1.w), d1, a7);
                a0 = __builtin_fmaf(bflo(u2.x), d2, a0); a1 = __builtin_fmaf(bfhi(u2.x), d2, a1);
                a2 = __builtin_fmaf(bflo(u2.y), d2, a2); a3 = __builtin_fmaf(bfhi(u2.y), d2, a3);
                a4 = __builtin_fmaf(bflo(u2.z), d2, a4); a5 = __builtin_fmaf(bfhi(u2.z), d2, a5);
                a6 = __builtin_fmaf(bflo(u2.w), d2, a6); a7 = __builtin_fmaf(bfhi(u2.w), d2, a7);
                a0 = __builtin_fmaf(bflo(u3.x), d3, a0); a1 = __builtin_fmaf(bfhi(u3.x), d3, a1);
                a2 = __builtin_fmaf(bflo(u3.y), d3, a2); a3 = __builtin_fmaf(bfhi(u3.y), d3, a3);
                a4 = __builtin_fmaf(bflo(u3.z), d3, a4); a5 = __builtin_fmaf(bfhi(u3.z), d3, a5);
                a6 = __builtin_fmaf(bflo(u3.w), d3, a6); a7 = __builtin_fmaf(bfhi(u3.w), d3, a7);
            }
        }
        uint4 o;
        o.x = pack2(a0 * di, a1 * di);
        o.y = pack2(a2 * di, a3 * di);
        o.z = pack2(a4 * di, a5 * di);
        o.w = pack2(a6 * di, a7 * di);
        *(uint4*)&aggs[node_local * 136 + lane16 * 8] = o;  // 16 B LDS store
    }
    __syncthreads();

    // ---- GEMM phase: wave -> (row strip, col half) ----
    const int wave = t >> 6, l = t & 63;
    const int strip = wave >> 1;   // 0/1: rows strip*16 .. +15
    const int colh = wave & 1;     // 0/1: cols colh*64 .. +63
    const int kq = l >> 4;
    const int lc = l & 15;
    const int row_local = strip * 16 + lc;

    float4v acc[4];
    for (int ct = 0; ct < 4; ++ct) acc[ct] = (float4v){0.f, 0.f, 0.f, 0.f};
    for (int kc = 0; kc < 4; ++kc) {
        short8 a = *(const short8*)(aggs + row_local * 136 + kc * 32 + kq * 8);
        for (int ct = 0; ct < 4; ++ct) {
            int ctg = colh * 4 + ct;
            short8 b = *(const short8*)(w1f + (ctg * 4 + kc) * 512 + l * 8);
            acc[ct] = __builtin_amdgcn_mfma_f32_16x16x32_bf16(a, b, acc[ct], 0, 0, 0);
        }
    }
    const int drow0 = strip * 16 + kq * 4;
    for (int ct = 0; ct < 4; ++ct) {
        int c = colh * 64 + ct * 16 + lc;
        float bb = b1[c];
        for (int r = 0; r < 4; ++r) {
            float v = fast_tanh(acc[ct][r] + bb);
            hs[(drow0 + r) * 136 + c] = f2bf(v);
        }
    }
    __syncthreads();

    float4v acc2[4];
    for (int ct = 0; ct < 4; ++ct) acc2[ct] = (float4v){0.f, 0.f, 0.f, 0.f};
    for (int kc = 0; kc < 4; ++kc) {
        short8 a = *(const short8*)(hs + row_local * 136 + kc * 32 + kq * 8);
        for (int ct = 0; ct < 4; ++ct) {
            int ctg = colh * 4 + ct;
            short8 b = *(const short8*)(w2f + (ctg * 4 + kc) * 512 + l * 8);
            acc2[ct] = __builtin_amdgcn_mfma_f32_16x16x32_bf16(a, b, acc2[ct], 0, 0, 0);
        }
    }
    const int orow0 = blockIdx.x * BROWS + drow0;
    for (int ct = 0; ct < 4; ++ct) {
        int c = colh * 64 + ct * 16 + lc;
        float bb = b2[c];
        for (int r = 0; r < 4; ++r) {
            int orow = orow0 + r;
            if (orow < n) out[(size_t)orow * DFEAT + c] = acc2[ct][r] + bb;
        }
    }
}

static inline size_t align256(size_t v) { return (v + 255) & ~(size_t)255; }

extern "C" void kernel_launch(void* const* d_in, const int* in_sizes, int n_in,
                              void* d_out, int out_size, void* d_ws, size_t ws_size,
                              hipStream_t stream) {
    const float* x  = (const float*)d_in[0];
    const int*   ei = (const int*)d_in[1];
    const float* W1 = (const float*)d_in[2];
    const float* b1 = (const float*)d_in[3];
    const float* W2 = (const float*)d_in[4];
    const float* b2 = (const float*)d_in[5];
    float* out = (float*)d_out;

    const int N = in_sizes[0] / DFEAT;   // 50000
    const int E = in_sizes[1] / 2;       // 640000
    const int* src = ei;
    const int* dst = ei + E;

    char* ws = (char*)d_ws;
    size_t off = 0;
    int* cnt8 = (int*)(ws + off);   off += align256((size_t)NPART * N * 4);
    int* col8 = (int*)(ws + off);   off += align256((size_t)NPART * N * CAP8 * 4);
    uint2* pcnt = (uint2*)(ws + off); off += align256((size_t)N * 8);
    float* dinv = (float*)(ws + off); off += align256((size_t)(N + 1) * 4);
    unsigned short* xb  = (unsigned short*)(ws + off); off += align256((size_t)(N + 1) * DFEAT * 2);
    unsigned short* w1f = (unsigned short*)(ws + off); off += align256((size_t)DFEAT * DFEAT * 2);
    unsigned short* w2f = (unsigned short*)(ws + off); off += align256((size_t)DFEAT * DFEAT * 2);

    const int n32 = N * 32;  // conversion threads (float4 each)
    int t1 = n32 + 32;
    if (t1 < E) t1 = E;
    if (t1 < 2 * DFEAT * DFEAT) t1 = 2 * DFEAT * DFEAT;

    hipMemsetAsync(cnt8, 0, (size_t)NPART * N * 4, stream);
    k1_scatter_conv<<<(t1 + 255) / 256, 256, 0, stream>>>(
        src, dst, cnt8, col8, x, (unsigned int*)xb, W1, W2, w1f, w2f, E, n32, N);
    k2_desc<<<(N + 1 + 255) / 256, 256, 0, stream>>>(cnt8, pcnt, dinv, N);
    k_agg_gemm<<<(N + BROWS - 1) / BROWS, 256, 0, stream>>>(
        (const uint4*)xb, pcnt, dinv, col8, w1f, b1, w2f, b2, out, N);
}

// Round 5
// 166.450 us; speedup vs baseline: 1.0446x; 1.0446x over previous
//
#include <hip/hip_runtime.h>

// GCN 2-layer. out = tanh((Â x) W1 + b1) W2 + b2, with Â(xW1)=(Âx)W1.
// Round 16: R14 structure with PARALLEL compaction (the R14 prep was a serial
// per-node loop ~25us; R15's direct-col8 agg blew VGPR 40->96, occ 34->17%).
//  k_scatter8: partition p=blockIdx&7 (~XCD) -> cnt8[p][N], col8[p][N][16]
//    (XCD-local L2, no dirty-line bounce) + W frag swizzle.
//  k_prep: (i<8N) 8 threads/node compact col8 -> col[node][48] via shfl
//    prefix-sum; lane7 writes cnt + sentinel-pads to mult of 8.
//    (i<32N) xb = bf16(x * dinv) (degree via shfl-reduced cnt8) + zero row.
//  k_agg_gemm: R13 lean gather (pre-folded dinv, no cnt loads, no clamps,
//    2-quad unroll = 8 gathers in flight) + GEMM1(+bias+tanh) + GEMM2(+bias).
// 4 graph nodes: memset(cnt8) | scatter8 | prep | agg.
// ws: cnt8(1.6MB) | cnt(0.2) | col8(25.6) | col(9.6) | xb(12.8) | w1f | w2f

#define DFEAT 128
#define CAP 48      // total bucket capacity per node (mult of 8, int4-aligned)
#define CAP8 16     // per-partition capacity (lambda=1.6, P(overflow)~1e-12)
#define NPART 8
#define BROWS 32    // nodes per block

typedef __attribute__((ext_vector_type(8))) short short8;
typedef __attribute__((ext_vector_type(4))) float float4v;

__device__ __forceinline__ float bflo(unsigned int u) {
    union { unsigned int i; float f; } v; v.i = u << 16; return v.f;
}
__device__ __forceinline__ float bfhi(unsigned int u) {
    union { unsigned int i; float f; } v; v.i = u & 0xffff0000u; return v.f;
}
__device__ __forceinline__ unsigned short f2bf(float f) {
    union { unsigned int i; float f; } v; v.f = f;
    unsigned int r = v.i + 0x7fffu + ((v.i >> 16) & 1u);  // RNE
    return (unsigned short)(r >> 16);
}
__device__ __forceinline__ unsigned int pack2(float a, float b) {
    return (unsigned int)f2bf(a) | ((unsigned int)f2bf(b) << 16);
}
// tanh(x) = 1 - 2/(exp(2x)+1); exact at +-inf.
__device__ __forceinline__ float fast_tanh(float x) {
    float e = __expf(2.0f * x);
    float r = __builtin_amdgcn_rcpf(e + 1.0f);  // raw v_rcp_f32, ~1 ulp
    return __builtin_fmaf(-2.0f, r, 1.0f);
}

// Partitioned count+scatter (+ W frag swizzle). Block b writes only
// partition b&7: cnt8[p*n+d], col8[(p*n+d)*CAP8 + slot].
__global__ void k_scatter8(const int* __restrict__ src, const int* __restrict__ dst,
                           int* __restrict__ cnt8, int* __restrict__ col8,
                           const float* __restrict__ W1, const float* __restrict__ W2,
                           unsigned short* __restrict__ w1f, unsigned short* __restrict__ w2f,
                           int e, int n) {
    int i = blockIdx.x * blockDim.x + threadIdx.x;
    if (i < 2 * DFEAT * DFEAT) {  // W fragment swizzle (B-operand layout)
        int which = i >> 14;
        int idx = i & 16383;
        int k = idx >> 7, nn = idx & 127;
        int f = ((nn >> 4) << 2) + (k >> 5);
        int lane = (nn & 15) | (((k >> 3) & 3) << 4);
        int j = k & 7;
        int o = f * 512 + lane * 8 + j;
        if (which == 0) w1f[o] = f2bf(W1[idx]);
        else            w2f[o] = f2bf(W2[idx]);
    }
    if (i < e) {
        int p = blockIdx.x & (NPART - 1);  // ~XCD id (perf-only assumption)
        int d = dst[i];
        int cell = p * n + d;
        int q = atomicAdd(&cnt8[cell], 1);
        if (q < CAP8) col8[(size_t)cell * CAP8 + q] = src[i];
    }
}

// Parallel compaction + conversion.
//  i < 8N : thread (node, p) copies its partition bucket into col[node][48]
//           at the shfl-prefix-summed offset; lane7 writes cnt + sentinel pad.
//  i < 32N: xb = bf16(x * dinv); degree via shfl_xor sum of clamped cnt8.
//  i in [32N, 32N+32): zero row xb[n] (sentinel target, dinv weight 0 free).
__global__ void k_prep(const float* __restrict__ x, const int* __restrict__ cnt8,
                       int* __restrict__ cnt, const int* __restrict__ col8,
                       int* __restrict__ col, unsigned int* __restrict__ xb2, int n) {
    int i = blockIdx.x * blockDim.x + threadIdx.x;
    const int n32 = n * 32;
    if (i < n * NPART) {  // parallel compaction (8-groups never straddle cut)
        int node = i >> 3, p = i & 7;
        int cell = p * n + node;
        int c = min(cnt8[cell], CAP8);
        int pre = c;  // inclusive scan over the 8-lane group
        #pragma unroll
        for (int d = 1; d < 8; d <<= 1) {
            int v = __shfl_up(pre, d, 8);
            if (p >= d) pre += v;
        }
        int prefix = pre - c;
        const int* bp = col8 + (size_t)cell * CAP8;
        int* cw = col + (size_t)node * CAP;
        for (int j = 0; j < c; ++j) {
            int idx = prefix + j;
            if (idx < CAP) cw[idx] = bp[j];
        }
        if (p == 7) {
            int total = pre;       // full degree (sum of clamped partitions)
            cnt[node] = total;
            int k = min(total, CAP);
            int kp = (k + 7) & ~7; // <= CAP (CAP % 8 == 0)
            for (; k < kp; ++k) cw[k] = n;  // sentinel pad to multiple of 8
        }
    }
    if (i < n32) {  // conversion: 4 floats/thread, 32 threads/node
        int node = i >> 5;
        int q = i & 7;
        int deg = min(cnt8[q * n + node], CAP8);  // 8-way redundant, coalesced
        deg += __shfl_xor(deg, 1, 8);
        deg += __shfl_xor(deg, 2, 8);
        deg += __shfl_xor(deg, 4, 8);
        float di = rsqrtf((float)(deg + 1));  // +1 self-loop
        float4 v = ((const float4*)x)[i];
        xb2[i * 2]     = pack2(v.x * di, v.y * di);
        xb2[i * 2 + 1] = pack2(v.z * di, v.w * di);
    } else if (i < n32 + 32) {  // zero row xb[n]
        xb2[i * 2] = 0u;
        xb2[i * 2 + 1] = 0u;
    }
}

// Fused: per-block aggregation of BROWS nodes into LDS, then
// GEMM1(+bias+tanh) -> LDS -> GEMM2(+bias) -> fp32 out.
// Gather: 2 passes x (16 nodes x 16 lanes), uint4 gathers, 2-quad unroll
// (8 rows in flight); buckets sentinel-padded to 8 -> uniform loop, no clamps.
// GEMM: wave w = (strip=w>>1) x (colh=w&1); A[m=lane&15][k=(lane>>4)*8+j];
// D: col=lane&15, row=(lane>>4)*4+reg (m89-verified layouts).
__global__ __launch_bounds__(256) void k_agg_gemm(
    const uint4* __restrict__ xb4, const int* __restrict__ cnt,
    const int* __restrict__ col,
    const unsigned short* __restrict__ w1f, const float* __restrict__ b1,
    const unsigned short* __restrict__ w2f, const float* __restrict__ b2,
    float* __restrict__ out, int n) {
    __shared__ unsigned short aggs[BROWS * 136];  // 8.7 KB, 136-pitch
    __shared__ unsigned short hs[BROWS * 136];    // 8.7 KB
    const int t = threadIdx.x;

    // ---- aggregation phase ----
    const int lane16 = t & 15;
    const int sub = t >> 4;  // 0..15
    for (int g = 0; g < BROWS / 16; ++g) {
        int node_local = g * 16 + sub;
        int node = blockIdx.x * BROWS + node_local;
        int nodec = min(node, n - 1);
        int raw = cnt[nodec];
        int deg = min(raw, CAP);
        float di = rsqrtf((float)(raw + 1));  // bitwise-matches prep's dinv
        uint4 v = xb4[(size_t)nodec * 16 + lane16];  // self term (dinv folded)
        float a0 = bflo(v.x), a1 = bfhi(v.x), a2 = bflo(v.y), a3 = bfhi(v.y);
        float a4 = bflo(v.z), a5 = bfhi(v.z), a6 = bflo(v.w), a7 = bfhi(v.w);
        const int4* col4 = (const int4*)(col + (size_t)nodec * CAP);
        int nq2 = (deg + 7) >> 3;  // 2 quads/iter; tails sentinel-padded to 8
        for (int q = 0; q < nq2; ++q) {
            int4 sa = col4[2 * q];
            int4 sb = col4[2 * q + 1];
            uint4 u0 = xb4[(size_t)sa.x * 16 + lane16];
            uint4 u1 = xb4[(size_t)sa.y * 16 + lane16];
            uint4 u2 = xb4[(size_t)sa.z * 16 + lane16];
            uint4 u3 = xb4[(size_t)sa.w * 16 + lane16];
            uint4 u4 = xb4[(size_t)sb.x * 16 + lane16];
            uint4 u5 = xb4[(size_t)sb.y * 16 + lane16];
            uint4 u6 = xb4[(size_t)sb.z * 16 + lane16];
            uint4 u7 = xb4[(size_t)sb.w * 16 + lane16];
            a0 += bflo(u0.x); a1 += bfhi(u0.x); a2 += bflo(u0.y); a3 += bfhi(u0.y);
            a4 += bflo(u0.z); a5 += bfhi(u0.z); a6 += bflo(u0.w); a7 += bfhi(u0.w);
            a0 += bflo(u1.x); a1 += bfhi(u1.x); a2 += bflo(u1.y); a3 += bfhi(u1.y);
            a4 += bflo(u1.z); a5 += bfhi(u1.z); a6 += bflo(u1.w); a7 += bfhi(u1.w);
            a0 += bflo(u2.x); a1 += bfhi(u2.x); a2 += bflo(u2.y); a3 += bfhi(u2.y);
            a4 += bflo(u2.z); a5 += bfhi(u2.z); a6 += bflo(u2.w); a7 += bfhi(u2.w);
            a0 += bflo(u3.x); a1 += bfhi(u3.x); a2 += bflo(u3.y); a3 += bfhi(u3.y);
            a4 += bflo(u3.z); a5 += bfhi(u3.z); a6 += bflo(u3.w); a7 += bfhi(u3.w);
            a0 += bflo(u4.x); a1 += bfhi(u4.x); a2 += bflo(u4.y); a3 += bfhi(u4.y);
            a4 += bflo(u4.z); a5 += bfhi(u4.z); a6 += bflo(u4.w); a7 += bfhi(u4.w);
            a0 += bflo(u5.x); a1 += bfhi(u5.x); a2 += bflo(u5.y); a3 += bfhi(u5.y);
            a4 += bflo(u5.z); a5 += bfhi(u5.z); a6 += bflo(u5.w); a7 += bfhi(u5.w);
            a0 += bflo(u6.x); a1 += bfhi(u6.x); a2 += bflo(u6.y); a3 += bfhi(u6.y);
            a4 += bflo(u6.z); a5 += bfhi(u6.z); a6 += bflo(u6.w); a7 += bfhi(u6.w);
            a0 += bflo(u7.x); a1 += bfhi(u7.x); a2 += bflo(u7.y); a3 += bfhi(u7.y);
            a4 += bflo(u7.z); a5 += bfhi(u7.z); a6 += bflo(u7.w); a7 += bfhi(u7.w);
        }
        uint4 o;
        o.x = pack2(a0 * di, a1 * di);
        o.y = pack2(a2 * di, a3 * di);
        o.z = pack2(a4 * di, a5 * di);
        o.w = pack2(a6 * di, a7 * di);
        *(uint4*)&aggs[node_local * 136 + lane16 * 8] = o;  // 16 B LDS store
    }
    __syncthreads();

    // ---- GEMM phase: wave -> (row strip, col half) ----
    const int wave = t >> 6, l = t & 63;
    const int strip = wave >> 1;   // 0/1: rows strip*16 .. +15
    const int colh = wave & 1;     // 0/1: cols colh*64 .. +63
    const int kq = l >> 4;
    const int lc = l & 15;
    const int row_local = strip * 16 + lc;

    float4v acc[4];
    for (int ct = 0; ct < 4; ++ct) acc[ct] = (float4v){0.f, 0.f, 0.f, 0.f};
    for (int kc = 0; kc < 4; ++kc) {
        short8 a = *(const short8*)(aggs + row_local * 136 + kc * 32 + kq * 8);
        for (int ct = 0; ct < 4; ++ct) {
            int ctg = colh * 4 + ct;
            short8 b = *(const short8*)(w1f + (ctg * 4 + kc) * 512 + l * 8);
            acc[ct] = __builtin_amdgcn_mfma_f32_16x16x32_bf16(a, b, acc[ct], 0, 0, 0);
        }
    }
    const int drow0 = strip * 16 + kq * 4;
    for (int ct = 0; ct < 4; ++ct) {
        int c = colh * 64 + ct * 16 + lc;
        float bb = b1[c];
        for (int r = 0; r < 4; ++r) {
            float v = fast_tanh(acc[ct][r] + bb);
            hs[(drow0 + r) * 136 + c] = f2bf(v);
        }
    }
    __syncthreads();

    float4v acc2[4];
    for (int ct = 0; ct < 4; ++ct) acc2[ct] = (float4v){0.f, 0.f, 0.f, 0.f};
    for (int kc = 0; kc < 4; ++kc) {
        short8 a = *(const short8*)(hs + row_local * 136 + kc * 32 + kq * 8);
        for (int ct = 0; ct < 4; ++ct) {
            int ctg = colh * 4 + ct;
            short8 b = *(const short8*)(w2f + (ctg * 4 + kc) * 512 + l * 8);
            acc2[ct] = __builtin_amdgcn_mfma_f32_16x16x32_bf16(a, b, acc2[ct], 0, 0, 0);
        }
    }
    const int orow0 = blockIdx.x * BROWS + drow0;
    for (int ct = 0; ct < 4; ++ct) {
        int c = colh * 64 + ct * 16 + lc;
        float bb = b2[c];
        for (int r = 0; r < 4; ++r) {
            int orow = orow0 + r;
            if (orow < n) out[(size_t)orow * DFEAT + c] = acc2[ct][r] + bb;
        }
    }
}

static inline size_t align256(size_t v) { return (v + 255) & ~(size_t)255; }

extern "C" void kernel_launch(void* const* d_in, const int* in_sizes, int n_in,
                              void* d_out, int out_size, void* d_ws, size_t ws_size,
                              hipStream_t stream) {
    const float* x  = (const float*)d_in[0];
    const int*   ei = (const int*)d_in[1];
    const float* W1 = (const float*)d_in[2];
    const float* b1 = (const float*)d_in[3];
    const float* W2 = (const float*)d_in[4];
    const float* b2 = (const float*)d_in[5];
    float* out = (float*)d_out;

    const int N = in_sizes[0] / DFEAT;   // 50000
    const int E = in_sizes[1] / 2;       // 640000
    const int* src = ei;
    const int* dst = ei + E;

    char* ws = (char*)d_ws;
    size_t off = 0;
    int* cnt8 = (int*)(ws + off); off += align256((size_t)NPART * N * 4);
    int* cnt  = (int*)(ws + off); off += align256((size_t)N * 4);
    int* col8 = (int*)(ws + off); off += align256((size_t)NPART * N * CAP8 * 4);
    int* col  = (int*)(ws + off); off += align256((size_t)N * CAP * 4);
    unsigned short* xb  = (unsigned short*)(ws + off); off += align256((size_t)(N + 1) * DFEAT * 2);
    unsigned short* w1f = (unsigned short*)(ws + off); off += align256((size_t)DFEAT * DFEAT * 2);
    unsigned short* w2f = (unsigned short*)(ws + off); off += align256((size_t)DFEAT * DFEAT * 2);

    int t1 = E > 2 * DFEAT * DFEAT ? E : 2 * DFEAT * DFEAT;
    int t2 = N * 32 + 32;  // covers compaction (8N), conversion (32N), zero row

    hipMemsetAsync(cnt8, 0, (size_t)NPART * N * 4, stream);
    k_scatter8<<<(t1 + 255) / 256, 256, 0, stream>>>(
        src, dst, cnt8, col8, W1, W2, w1f, w2f, E, N);
    k_prep<<<(t2 + 255) / 256, 256, 0, stream>>>(
        x, cnt8, cnt, col8, col, (unsigned int*)xb, N);
    k_agg_gemm<<<(N + BROWS - 1) / BROWS, 256, 0, stream>>>(
        (const uint4*)xb, cnt, col, w1f, b1, w2f, b2, out, N);
}